// Round 1
// baseline (7903.554 us; speedup 1.0000x reference)
//
#include <hip/hip_runtime.h>

// ---------------------------------------------------------------------------
// RNN_69526930588180: 3-layer SimpleRNN (tanh), B=256, T=256, D=64, H=512.
//
// Design (round 0):
//  * 3 persistent "rec" kernels (one per layer) + tiny head GEMV.
//  * Grid 256 WGs x 256 thr: 16 batch-groups (Bc=16 rows) x 16 col-groups
//    (Hc=32 cols). Wh/Wx column slices live in LDS as bf16 for the whole
//    kernel (rotated layout -> <=2-way LDS bank conflicts, free).
//  * Input projection fused: waves 0-1 compute h_{t-1}@Wh, waves 2-3 compute
//    x_t@Wx (or seq_in_t@Wx), partial C tiles summed via LDS, +bias, tanh,
//    store bf16 h_t to the sequence buffer.
//  * Cross-WG step dependency (within a batch-group, 16 WGs) via per-step
//    counters: release-fence + relaxed atomicAdd (producer), relaxed spin +
//    acquire-fence (consumer), agent scope => correct across XCDs.
//    Sequence buffer is append-only over t => no WAR hazards.
//  * Workspace: seqA (67MB bf16) + seqB (67MB) + counters. Layer2 reuses seqA.
// ---------------------------------------------------------------------------

typedef unsigned short u16;
typedef unsigned int   u32;

typedef __attribute__((ext_vector_type(8))) short short8;
typedef __attribute__((ext_vector_type(4))) float f32x4;

#define N_B 256
#define N_T 256
#define N_D 64
#define N_H 512
#define GB  16   // batch groups
#define GC  16   // column groups
#define BC  16   // rows per group
#define HC  32   // cols per WG

__device__ __forceinline__ u16 f2bf(float f) {
  union { float f; u32 u; } v; v.f = f;
  u32 u = v.u;
  u += 0x7fffu + ((u >> 16) & 1u);   // RNE
  return (u16)(u >> 16);
}
__device__ __forceinline__ float bf2f(u16 h) {
  union { u32 u; float f; } v; v.u = ((u32)h) << 16;
  return v.f;
}
__device__ __forceinline__ short8 ld8(const u16* p) {
  return *(const short8*)p;
}
__device__ __forceinline__ short8 cvt8(const float* p) {
  short8 r;
#pragma unroll
  for (int j = 0; j < 8; ++j) r[j] = (short)f2bf(p[j]);
  return r;
}

// One layer of the RNN. in_ptr: L0 ? const float* x [B,T,64] : const u16* seq_in [T,B,512].
// out_seq: u16 [T,B,512]. cnt: GB*N_T counters (zeroed before launch).
template <bool L0>
__global__ __launch_bounds__(256, 1)
void rec_kernel(const void* __restrict__ in_ptr, u16* __restrict__ out_seq,
                const float* __restrict__ Wx, const float* __restrict__ Wh,
                const float* __restrict__ bias, u32* __restrict__ cnt) {
  constexpr int KIN = L0 ? N_D : N_H;
  const int i    = blockIdx.x >> 4;   // batch group
  const int j    = blockIdx.x & 15;   // column group
  const int tid  = threadIdx.x;
  const int lane = tid & 63;
  const int w    = tid >> 6;
  const int quad = lane >> 4;
  const int l16  = lane & 15;
  const int gemm = w >> 1;            // 0: recurrent h@Wh, 1: input proj
  const int nt   = w & 1;             // 16-col tile within WG's 32
  const int n_local = nt * 16 + l16;

  __shared__ u16   WhT[HC][N_H];      // [n][k], k rotated by 8*n
  __shared__ u16   WxT[HC][KIN];      // [n][k], k rotated by 8*n
  __shared__ float bsh[HC];
  __shared__ float Cbuf[2][16][33];   // [gemm][row][col], padded

  // Stage weight slices (cols j*32 .. +32) into LDS, bf16, transposed+rotated.
  for (int e = tid; e < HC * N_H; e += 256) {
    int n = e & 31, k = e >> 5;
    WhT[n][(k + 8 * n) & (N_H - 1)] = f2bf(Wh[k * N_H + j * HC + n]);
  }
  for (int e = tid; e < HC * KIN; e += 256) {
    int n = e & 31, k = e >> 5;
    WxT[n][(k + 8 * n) & (KIN - 1)] = f2bf(Wx[k * N_H + j * HC + n]);
  }
  if (tid < HC) bsh[tid] = bias[j * HC + tid];
  __syncthreads();

  bool dead = false;  // sticky bail-out to avoid hangs if co-residency breaks

  for (int t = 0; t < N_T; ++t) {
    f32x4 acc = {0.f, 0.f, 0.f, 0.f};

    if (gemm == 0) {
      if (t > 0) {
        // Wait for all 16 WGs of group i to have published h_{t-1}.
        if (!dead) {
          u32 it = 0;
          while (__hip_atomic_load(&cnt[i * N_T + (t - 1)], __ATOMIC_RELAXED,
                                   __HIP_MEMORY_SCOPE_AGENT) < (u32)GC) {
            __builtin_amdgcn_s_sleep(2);
            if (++it > (1u << 22)) { dead = true; break; }
          }
        }
        __builtin_amdgcn_fence(__ATOMIC_ACQUIRE, "agent");
        const u16* ap = out_seq +
            ((size_t)(t - 1) * N_B + i * BC + l16) * N_H + quad * 8;
#pragma unroll
        for (int kt = 0; kt < N_H / 32; ++kt) {
          short8 a = ld8(ap + kt * 32);
          short8 b = ld8(&WhT[n_local][(kt * 32 + quad * 8 + 8 * n_local) & (N_H - 1)]);
          acc = __builtin_amdgcn_mfma_f32_16x16x32_bf16(a, b, acc, 0, 0, 0);
        }
      }
    } else {
      if (L0) {
        const float* xp = (const float*)in_ptr +
            ((size_t)(i * BC + l16) * N_T + t) * N_D + quad * 8;
#pragma unroll
        for (int kt = 0; kt < KIN / 32; ++kt) {
          short8 a = cvt8(xp + kt * 32);
          short8 b = ld8(&WxT[n_local][(kt * 32 + quad * 8 + 8 * n_local) & (KIN - 1)]);
          acc = __builtin_amdgcn_mfma_f32_16x16x32_bf16(a, b, acc, 0, 0, 0);
        }
      } else {
        const u16* sp = (const u16*)in_ptr +
            ((size_t)t * N_B + i * BC + l16) * N_H + quad * 8;
#pragma unroll
        for (int kt = 0; kt < KIN / 32; ++kt) {
          short8 a = ld8(sp + kt * 32);
          short8 b = ld8(&WxT[n_local][(kt * 32 + quad * 8 + 8 * n_local) & (KIN - 1)]);
          acc = __builtin_amdgcn_mfma_f32_16x16x32_bf16(a, b, acc, 0, 0, 0);
        }
      }
    }

    // C/D layout (m89): col = lane&15, row = quad*4 + reg.
    {
      int rowb = quad * 4;
      Cbuf[gemm][rowb + 0][n_local] = acc[0];
      Cbuf[gemm][rowb + 1][n_local] = acc[1];
      Cbuf[gemm][rowb + 2][n_local] = acc[2];
      Cbuf[gemm][rowb + 3][n_local] = acc[3];
    }
    __syncthreads();

    // Combine: u = h@Wh + x@Wx + b; h = tanh(u); store bf16 pair.
    {
      int r  = tid >> 4;           // 0..15
      int c0 = (tid & 15) * 2;     // 0..30
      float u0 = Cbuf[0][r][c0]     + Cbuf[1][r][c0]     + bsh[c0];
      float u1 = Cbuf[0][r][c0 + 1] + Cbuf[1][r][c0 + 1] + bsh[c0 + 1];
      u32 pk = (u32)f2bf(tanhf(u0)) | ((u32)f2bf(tanhf(u1)) << 16);
      *(u32*)&out_seq[((size_t)t * N_B + i * BC + r) * N_H + j * HC + c0] = pk;
    }
    __syncthreads();  // all stores drained (vmcnt(0) before s_barrier)

    if (tid == 0) {
      __builtin_amdgcn_fence(__ATOMIC_RELEASE, "agent");  // buffer_wbl2: publish WG stores
      __hip_atomic_fetch_add(&cnt[i * N_T + t], 1u, __ATOMIC_RELAXED,
                             __HIP_MEMORY_SCOPE_AGENT);
    }
  }
}

// out[b] = seq2[T-1][b][:] . Wf + bf
__global__ void head_kernel(const u16* __restrict__ seq2, const float* __restrict__ Wf,
                            const float* __restrict__ bf, float* __restrict__ out) {
  int b    = blockIdx.x;
  int lane = threadIdx.x;  // 64
  const u16* hrow = seq2 + ((size_t)(N_T - 1) * N_B + b) * N_H;
  float s = 0.f;
#pragma unroll
  for (int r = 0; r < N_H / 64; ++r) {
    int idx = lane * 8 + r;  // note: lane*8+r covers 0..511 uniquely for r<8
    s += bf2f(hrow[idx]) * Wf[idx];
  }
#pragma unroll
  for (int off = 32; off > 0; off >>= 1) s += __shfl_down(s, off);
  if (lane == 0) out[b] = s + bf[0];
}

extern "C" void kernel_launch(void* const* d_in, const int* in_sizes, int n_in,
                              void* d_out, int out_size, void* d_ws, size_t ws_size,
                              hipStream_t stream) {
  const float* x   = (const float*)d_in[0];
  const float* Wx0 = (const float*)d_in[1];
  const float* Wh0 = (const float*)d_in[2];
  const float* b0  = (const float*)d_in[3];
  const float* Wx1 = (const float*)d_in[4];
  const float* Wh1 = (const float*)d_in[5];
  const float* b1  = (const float*)d_in[6];
  const float* Wx2 = (const float*)d_in[7];
  const float* Wh2 = (const float*)d_in[8];
  const float* b2  = (const float*)d_in[9];
  const float* Wf  = (const float*)d_in[10];
  const float* bf  = (const float*)d_in[11];
  float* out = (float*)d_out;

  const size_t SEQ_BYTES = (size_t)N_T * N_B * N_H * sizeof(u16);  // 67,108,864
  const size_t CNT_ELEMS = (size_t)3 * GB * N_T;                   // 12,288
  if (ws_size < 2 * SEQ_BYTES + CNT_ELEMS * sizeof(u32)) return;   // loud fail

  char* ws  = (char*)d_ws;
  u16* seqA = (u16*)(ws);
  u16* seqB = (u16*)(ws + SEQ_BYTES);
  u32* cnt  = (u32*)(ws + 2 * SEQ_BYTES);

  hipMemsetAsync(cnt, 0, CNT_ELEMS * sizeof(u32), stream);

  rec_kernel<true ><<<256, 256, 0, stream>>>((const void*)x,    seqA, Wx0, Wh0, b0, cnt);
  rec_kernel<false><<<256, 256, 0, stream>>>((const void*)seqA, seqB, Wx1, Wh1, b1, cnt + GB * N_T);
  rec_kernel<false><<<256, 256, 0, stream>>>((const void*)seqB, seqA, Wx2, Wh2, b2, cnt + 2 * GB * N_T);
  head_kernel<<<N_B, 64, 0, stream>>>(seqA, Wf, bf, out);
}

// Round 2
// 3155.248 us; speedup vs baseline: 2.5049x; 2.5049x over previous
//
#include <hip/hip_runtime.h>

// ---------------------------------------------------------------------------
// RNN_69526930588180: 3-layer SimpleRNN (tanh), B=256, T=256, D=64, H=512.
//
// Round 2: remove per-step cache-maintenance fences (buffer_wbl2/buffer_inv
// storms were ~10.4us/step). Cross-WG h-state exchange now uses fine-grained
// LLC-coherent accesses:
//   * h stores:  global_store_dword ... sc0 sc1   (write-through to LLC)
//   * h loads:   global_load_dwordx4 ... sc0 sc1  (bypass L1/L2, read LLC)
//   * counters:  relaxed agent-scope atomics (LLC), per-wave publish after
//                s_waitcnt vmcnt(0). No fences anywhere in the loop.
//  Cooperative A-tile staging: the 16x512 bf16 h tile (contiguous 16KB) is
//  loaded by waves 0-1 (128B/lane, full lines) into a rotated LDS tile shared
//  by both recurrent waves. Spin-wait by lane 0 only (wave-level wait).
// ---------------------------------------------------------------------------

typedef unsigned short u16;
typedef unsigned int   u32;

typedef __attribute__((ext_vector_type(8))) short short8;
typedef __attribute__((ext_vector_type(4))) float f32x4;
typedef __attribute__((ext_vector_type(4))) int   i32x4;

#define N_B 256
#define N_T 256
#define N_D 64
#define N_H 512
#define GB  16   // batch groups
#define GC  16   // column groups
#define BC  16   // rows per group
#define HC  32   // cols per WG
#define CNT_TARGET 64  // 16 WGs x 4 waves publish per step

__device__ __forceinline__ u16 f2bf(float f) {
  union { float f; u32 u; } v; v.f = f;
  u32 u = v.u;
  u += 0x7fffu + ((u >> 16) & 1u);   // RNE
  return (u16)(u >> 16);
}
__device__ __forceinline__ float bf2f(u16 h) {
  union { u32 u; float f; } v; v.u = ((u32)h) << 16;
  return v.f;
}
__device__ __forceinline__ short8 ld8(const u16* p) {
  return *(const short8*)p;
}
__device__ __forceinline__ short8 cvt8(const float* p) {
  short8 r;
#pragma unroll
  for (int j = 0; j < 8; ++j) r[j] = (short)f2bf(p[j]);
  return r;
}

// One layer. in_ptr: L0 ? const float* x [B,T,64] : const u16* seq_in [T,B,512].
// out_seq: u16 [T,B,512]. cnt: GB*N_T counters (zeroed before launch).
template <bool L0>
__global__ __launch_bounds__(256, 1)
void rec_kernel(const void* __restrict__ in_ptr, u16* __restrict__ out_seq,
                const float* __restrict__ Wx, const float* __restrict__ Wh,
                const float* __restrict__ bias, u32* __restrict__ cnt) {
  constexpr int KIN = L0 ? N_D : N_H;
  const int i    = blockIdx.x >> 4;   // batch group
  const int j    = blockIdx.x & 15;   // column group
  const int tid  = threadIdx.x;
  const int lane = tid & 63;
  const int w    = tid >> 6;
  const int quad = lane >> 4;
  const int l16  = lane & 15;
  const int gemm = w >> 1;            // 0: recurrent h@Wh (waves 0-1), 1: input proj
  const int nt   = w & 1;             // 16-col tile within WG's 32
  const int n_local = nt * 16 + l16;

  __shared__ u16   WhT[HC][N_H];      // [n][k], k rotated by 8*n
  __shared__ u16   WxT[HC][KIN];      // [n][k], k rotated by 8*n
  __shared__ u16   Ash[BC][N_H];      // h_{t-1} tile, k rotated by 8*row
  __shared__ float bsh[HC];
  __shared__ float Cbuf[2][16][33];   // [gemm][row][col], padded

  // Stage weight slices (cols j*32 .. +32) into LDS, bf16, transposed+rotated.
  for (int e = tid; e < HC * N_H; e += 256) {
    int n = e & 31, k = e >> 5;
    WhT[n][(k + 8 * n) & (N_H - 1)] = f2bf(Wh[k * N_H + j * HC + n]);
  }
  for (int e = tid; e < HC * KIN; e += 256) {
    int n = e & 31, k = e >> 5;
    WxT[n][(k + 8 * n) & (KIN - 1)] = f2bf(Wx[k * N_H + j * HC + n]);
  }
  if (tid < HC) bsh[tid] = bias[j * HC + tid];
  __syncthreads();

  bool dead = false;  // sticky bail-out to avoid hangs if co-residency breaks

  for (int t = 0; t < N_T; ++t) {
    f32x4 acc = {0.f, 0.f, 0.f, 0.f};

    // ---- phase A: proj waves compute x_t@Wx; rec waves wait + stage A ----
    if (gemm == 1) {
      if (L0) {
        const float* xp = (const float*)in_ptr +
            ((size_t)(i * BC + l16) * N_T + t) * N_D + quad * 8;
#pragma unroll
        for (int kt = 0; kt < KIN / 32; ++kt) {
          short8 a = cvt8(xp + kt * 32);
          short8 b = ld8(&WxT[n_local][(kt * 32 + quad * 8 + 8 * n_local) & (KIN - 1)]);
          acc = __builtin_amdgcn_mfma_f32_16x16x32_bf16(a, b, acc, 0, 0, 0);
        }
      } else {
        const u16* sp = (const u16*)in_ptr +
            ((size_t)t * N_B + i * BC + l16) * N_H + quad * 8;
#pragma unroll
        for (int kt = 0; kt < KIN / 32; ++kt) {
          short8 a = ld8(sp + kt * 32);
          short8 b = ld8(&WxT[n_local][(kt * 32 + quad * 8 + 8 * n_local) & (KIN - 1)]);
          acc = __builtin_amdgcn_mfma_f32_16x16x32_bf16(a, b, acc, 0, 0, 0);
        }
      }
      {
        int rowb = quad * 4;
        Cbuf[1][rowb + 0][n_local] = acc[0];
        Cbuf[1][rowb + 1][n_local] = acc[1];
        Cbuf[1][rowb + 2][n_local] = acc[2];
        Cbuf[1][rowb + 3][n_local] = acc[3];
      }
    } else if (t > 0) {
      // Wave-level wait: lane 0 polls, other 63 lanes park at reconvergence.
      if (lane == 0 && !dead) {
        u32 it = 0;
        while (__hip_atomic_load(&cnt[i * N_T + (t - 1)], __ATOMIC_RELAXED,
                                 __HIP_MEMORY_SCOPE_AGENT) < (u32)CNT_TARGET) {
          __builtin_amdgcn_s_sleep(2);
          if (++it > (1u << 22)) { dead = true; break; }
        }
      }
      // Cooperative A-tile load: 128 threads x 128B contiguous, LLC-bypass.
      const u16* src = out_seq + ((size_t)(t - 1) * N_B + i * BC) * N_H + (size_t)tid * 64;
      i32x4 c0, c1, c2, c3, c4, c5, c6, c7;
      asm volatile(
          "global_load_dwordx4 %0, %8, off sc0 sc1\n\t"
          "global_load_dwordx4 %1, %8, off offset:16 sc0 sc1\n\t"
          "global_load_dwordx4 %2, %8, off offset:32 sc0 sc1\n\t"
          "global_load_dwordx4 %3, %8, off offset:48 sc0 sc1\n\t"
          "global_load_dwordx4 %4, %8, off offset:64 sc0 sc1\n\t"
          "global_load_dwordx4 %5, %8, off offset:80 sc0 sc1\n\t"
          "global_load_dwordx4 %6, %8, off offset:96 sc0 sc1\n\t"
          "global_load_dwordx4 %7, %8, off offset:112 sc0 sc1\n\t"
          "s_waitcnt vmcnt(0)"
          : "=&v"(c0), "=&v"(c1), "=&v"(c2), "=&v"(c3),
            "=&v"(c4), "=&v"(c5), "=&v"(c6), "=&v"(c7)
          : "v"(src)
          : "memory");
      const int row = tid >> 3;
      const int kb  = (tid & 7) * 64;
      i32x4 cc[8] = {c0, c1, c2, c3, c4, c5, c6, c7};
#pragma unroll
      for (int c = 0; c < 8; ++c) {
        int k = (kb + c * 8 + 8 * row) & (N_H - 1);
        *(i32x4*)&Ash[row][k] = cc[c];
      }
    }

    __syncthreads();  // b1: Ash staged; Cbuf[1] written

    // ---- phase B: recurrent h_{t-1}@Wh from LDS ----
    if (gemm == 0) {
      if (t > 0) {
#pragma unroll
        for (int kt = 0; kt < N_H / 32; ++kt) {
          short8 a = ld8(&Ash[l16][(kt * 32 + quad * 8 + 8 * l16) & (N_H - 1)]);
          short8 b = ld8(&WhT[n_local][(kt * 32 + quad * 8 + 8 * n_local) & (N_H - 1)]);
          acc = __builtin_amdgcn_mfma_f32_16x16x32_bf16(a, b, acc, 0, 0, 0);
        }
      }
      int rowb = quad * 4;
      Cbuf[0][rowb + 0][n_local] = acc[0];
      Cbuf[0][rowb + 1][n_local] = acc[1];
      Cbuf[0][rowb + 2][n_local] = acc[2];
      Cbuf[0][rowb + 3][n_local] = acc[3];
    }

    __syncthreads();  // b2: both Cbuf halves complete

    // ---- combine: u = h@Wh + x@Wx + b; h = tanh(u); LLC write-through ----
    {
      int r  = tid >> 4;           // 0..15
      int c0i = (tid & 15) * 2;    // 0..30
      float u0 = Cbuf[0][r][c0i]     + Cbuf[1][r][c0i]     + bsh[c0i];
      float u1 = Cbuf[0][r][c0i + 1] + Cbuf[1][r][c0i + 1] + bsh[c0i + 1];
      u32 pk = (u32)f2bf(tanhf(u0)) | ((u32)f2bf(tanhf(u1)) << 16);
      u32* dst = (u32*)&out_seq[((size_t)t * N_B + i * BC + r) * N_H + j * HC + c0i];
      asm volatile("global_store_dword %0, %1, off sc0 sc1" :: "v"(dst), "v"(pk) : "memory");
    }
    // Per-wave publish: drain this wave's stores (acked at LLC), then count.
    asm volatile("s_waitcnt vmcnt(0)" ::: "memory");
    if (lane == 0) {
      __hip_atomic_fetch_add(&cnt[i * N_T + t], 1u, __ATOMIC_RELAXED,
                             __HIP_MEMORY_SCOPE_AGENT);
    }

    __syncthreads();  // b3: combine reads done before next-iter Cbuf writes
  }
}

// out[b] = seq2[T-1][b][:] . Wf + bf
__global__ void head_kernel(const u16* __restrict__ seq2, const float* __restrict__ Wf,
                            const float* __restrict__ bf, float* __restrict__ out) {
  int b    = blockIdx.x;
  int lane = threadIdx.x;  // 64
  const u16* hrow = seq2 + ((size_t)(N_T - 1) * N_B + b) * N_H;
  float s = 0.f;
#pragma unroll
  for (int r = 0; r < N_H / 64; ++r) {
    int idx = lane * 8 + r;
    s += bf2f(hrow[idx]) * Wf[idx];
  }
#pragma unroll
  for (int off = 32; off > 0; off >>= 1) s += __shfl_down(s, off);
  if (lane == 0) out[b] = s + bf[0];
}

extern "C" void kernel_launch(void* const* d_in, const int* in_sizes, int n_in,
                              void* d_out, int out_size, void* d_ws, size_t ws_size,
                              hipStream_t stream) {
  const float* x   = (const float*)d_in[0];
  const float* Wx0 = (const float*)d_in[1];
  const float* Wh0 = (const float*)d_in[2];
  const float* b0  = (const float*)d_in[3];
  const float* Wx1 = (const float*)d_in[4];
  const float* Wh1 = (const float*)d_in[5];
  const float* b1  = (const float*)d_in[6];
  const float* Wx2 = (const float*)d_in[7];
  const float* Wh2 = (const float*)d_in[8];
  const float* b2  = (const float*)d_in[9];
  const float* Wf  = (const float*)d_in[10];
  const float* bf  = (const float*)d_in[11];
  float* out = (float*)d_out;

  const size_t SEQ_BYTES = (size_t)N_T * N_B * N_H * sizeof(u16);  // 67,108,864
  const size_t CNT_ELEMS = (size_t)3 * GB * N_T;                   // 12,288
  if (ws_size < 2 * SEQ_BYTES + CNT_ELEMS * sizeof(u32)) return;   // loud fail

  char* ws  = (char*)d_ws;
  u16* seqA = (u16*)(ws);
  u16* seqB = (u16*)(ws + SEQ_BYTES);
  u32* cnt  = (u32*)(ws + 2 * SEQ_BYTES);

  hipMemsetAsync(cnt, 0, CNT_ELEMS * sizeof(u32), stream);

  rec_kernel<true ><<<256, 256, 0, stream>>>((const void*)x,    seqA, Wx0, Wh0, b0, cnt);
  rec_kernel<false><<<256, 256, 0, stream>>>((const void*)seqA, seqB, Wx1, Wh1, b1, cnt + GB * N_T);
  rec_kernel<false><<<256, 256, 0, stream>>>((const void*)seqB, seqA, Wx2, Wh2, b2, cnt + 2 * GB * N_T);
  head_kernel<<<N_B, 64, 0, stream>>>(seqA, Wf, bf, out);
}